// Round 1
// baseline (414.172 us; speedup 1.0000x reference)
//
#include <hip/hip_runtime.h>
#include <math.h>

// ============================================================================
// re3: MLP-encode (3 layers + LayerNorm) of src/tgt, then fused
//      all-pairs-L2-distance + top-3-smallest + sum/2 ("state entropy").
//
// Pipeline:
//   prep_weights : W1/W2/W3 fp32 -> bf16 MFMA-fragment-linear in ws
//   encode_kernel: per 16-row wave, 3x (MFMA GEMM vs frag-linear W) + LN.
//                  Writes: src fp32 -> d_out, src/tgt bf16 frag-linear -> ws,
//                  row norms^2 -> ws.
//   dist_kernel  : 256 blocks x 8 waves; block = 64 src rows, full tgt scan.
//                  A-frags resident in VGPRs, B-frags straight from global
//                  (frag-linear => coalesced dwordx4), top-3 of
//                  (|t|^2 - 2 s.t) per row via fmin/fmed3 insert, final
//                  shfl + LDS merge, entropy = (d0+d1+d2)/2 -> d_out tail.
//
// MFMA 16x16x32 bf16 layouts (learn_hip m89/m97-verified):
//   A/B frag: lane l elem j  <->  row l&15, k = (l>>4)*8 + j   (16B contig)
//   D       : lane l reg  j  <->  row (l>>4)*4 + j, col l&15
// ============================================================================

typedef __attribute__((ext_vector_type(8))) short short8;
typedef __attribute__((ext_vector_type(4))) float floatx4;
typedef __attribute__((ext_vector_type(4))) unsigned short ushortx4;

#define MFMA16(a, b, c) __builtin_amdgcn_mfma_f32_16x16x32_bf16((a), (b), (c), 0, 0, 0)

// ---- ws layout (bytes) ----
static const size_t OFF_W1F  = 0;                       //  64 KB (16cf x 4ks x 64 x 8)
static const size_t OFF_W2F  = 65536;                   // 128 KB (16cf x 8ks x 64 x 8)
static const size_t OFF_W3F  = 196608;                  // 128 KB
static const size_t OFF_SRCF = 327680;                  //   8 MB (1024 tiles x 8ks x 64 x 8)
static const size_t OFF_TGTF = 327680 + 8388608;        //   8 MB
static const size_t OFF_S2   = 327680 + 2 * 8388608;    //  64 KB (row |y|^2, fp32)
static const size_t OFF_T2   = OFF_S2 + 65536;          //  64 KB

__device__ __forceinline__ unsigned short f2bf(float f) {
  unsigned int u = __float_as_uint(f);
  return (unsigned short)((u + 0x7FFFu + ((u >> 16) & 1u)) >> 16);  // RNE
}

// keep 3 smallest seen: t0<=t1<=t2, insert v  (1 min + 2 fmed3)
__device__ __forceinline__ void ins3(float& t0, float& t1, float& t2, float v) {
  float n0 = fminf(t0, v);
  float n1 = __builtin_amdgcn_fmed3f(t0, t1, v);
  float n2 = __builtin_amdgcn_fmed3f(t1, t2, v);
  t0 = n0; t1 = n1; t2 = n2;
}

// ---------------------------------------------------------------------------
// prep: W[k][c] fp32 -> bf16 frag-linear: elem j of frag ((cf*KS+ks)*64+l)
//       = W[ks*32 + (l>>4)*8 + j][cf*16 + (l&15)]
// ---------------------------------------------------------------------------
__global__ void prep_weights(const float* __restrict__ W1, const float* __restrict__ W2,
                             const float* __restrict__ W3, unsigned short* __restrict__ ws16) {
  int t = blockIdx.x * 256 + threadIdx.x;  // 20480 total
  const float* W;
  unsigned short* dst;
  int f, ksbits;
  if (t < 4096)       { W = W1; dst = ws16 + OFF_W1F / 2; f = t;         ksbits = 2; }
  else if (t < 12288) { W = W2; dst = ws16 + OFF_W2F / 2; f = t - 4096;  ksbits = 3; }
  else                { W = W3; dst = ws16 + OFF_W3F / 2; f = t - 12288; ksbits = 3; }
  int l  = f & 63;
  int fk = f >> 6;
  int ks = fk & ((1 << ksbits) - 1);
  int cf = fk >> ksbits;
  int k0 = ks * 32 + ((l >> 4) << 3);
  int c  = (cf << 4) + (l & 15);
  short8 v;
#pragma unroll
  for (int j = 0; j < 8; ++j) v[j] = (short)f2bf(W[(size_t)(k0 + j) * 256 + c]);
  *(short8*)(dst + (size_t)f * 8) = v;
}

// ---------------------------------------------------------------------------
// encode: blocks 0..255 = src rows, 256..511 = tgt rows; 4 independent waves
//         of 16 rows each. LDS per wave: x(4K) | h1(8K) | h2(8K), XOR-swizzled
//         (byte ^= (row&7)<<4) so A-frag ds_read_b128 is conflict-free.
// ---------------------------------------------------------------------------
__global__ __launch_bounds__(256) void encode_kernel(
    const float* __restrict__ xsrc, const float* __restrict__ xtgt,
    const float* __restrict__ b1, const float* __restrict__ b2, const float* __restrict__ b3,
    const float* __restrict__ gamma, const float* __restrict__ beta,
    float* __restrict__ out_src, unsigned short* __restrict__ ws16) {
  __shared__ unsigned short lds[4][10240];  // 80 KB
  const int tid = threadIdx.x, w = tid >> 6, l = tid & 63;
  const int blk = blockIdx.x;
  const bool is_src = blk < 256;
  const int row0 = ((blk & 255) << 6) + (w << 4);  // this wave's first global row
  const float* __restrict__ X = is_src ? xsrc : xtgt;
  unsigned short* __restrict__ fragout = ws16 + (is_src ? OFF_SRCF / 2 : OFF_TGTF / 2);
  float* __restrict__ nrm = (float*)(ws16 + (is_src ? OFF_S2 / 2 : OFF_T2 / 2));

  unsigned short* xb = &lds[w][0];
  unsigned short* h1 = &lds[w][2048];
  unsigned short* h2 = &lds[w][6144];

  // ---- stage x: 16 rows x 128 f32 -> bf16 LDS (swizzled) ----
#pragma unroll
  for (int i = 0; i < 8; ++i) {
    int idx = i * 64 + l;
    int r = idx >> 5, c4 = idx & 31;
    floatx4 xv = *(const floatx4*)(X + (size_t)(row0 + r) * 128 + c4 * 4);
    ushortx4 bv;
#pragma unroll
    for (int j = 0; j < 4; ++j) bv[j] = f2bf(xv[j]);
    int byte = (r * 256 + c4 * 8) ^ ((r & 7) << 4);
    *(ushortx4*)((char*)xb + byte) = bv;
  }

  // ---- layer 1: h1 = relu(x @ W1 + b1), K=128 ----
  short8 a1[4];
  {
    int row = l & 15, sw = (row & 7) << 4;
#pragma unroll
    for (int ks = 0; ks < 4; ++ks)
      a1[ks] = *(short8*)((char*)xb + ((row * 256 + ks * 64 + ((l >> 4) << 4)) ^ sw));
  }
  const unsigned short* W1f = ws16 + OFF_W1F / 2;
#pragma unroll
  for (int cf = 0; cf < 16; ++cf) {
    floatx4 acc = {0.f, 0.f, 0.f, 0.f};
#pragma unroll
    for (int ks = 0; ks < 4; ++ks) {
      short8 bfr = *(const short8*)(W1f + ((size_t)(cf * 4 + ks) * 64 + l) * 8);
      acc = MFMA16(a1[ks], bfr, acc);
    }
    int col = (cf << 4) + (l & 15);
    float bias = b1[col];
#pragma unroll
    for (int j = 0; j < 4; ++j) {
      float h = fmaxf(acc[j] + bias, 0.f);
      int row = ((l >> 4) << 2) + j;
      int byte = (row * 512 + col * 2) ^ ((row & 7) << 4);
      *(unsigned short*)((char*)h1 + byte) = f2bf(h);
    }
  }

  // ---- layer 2: h2 = relu(h1 @ W2 + b2), K=256 ----
  short8 a2[8];
  {
    int row = l & 15, sw = (row & 7) << 4;
#pragma unroll
    for (int ks = 0; ks < 8; ++ks)
      a2[ks] = *(short8*)((char*)h1 + ((row * 512 + ks * 64 + ((l >> 4) << 4)) ^ sw));
  }
  const unsigned short* W2f = ws16 + OFF_W2F / 2;
#pragma unroll
  for (int cf = 0; cf < 16; ++cf) {
    floatx4 acc = {0.f, 0.f, 0.f, 0.f};
#pragma unroll
    for (int ks = 0; ks < 8; ++ks) {
      short8 bfr = *(const short8*)(W2f + ((size_t)(cf * 8 + ks) * 64 + l) * 8);
      acc = MFMA16(a2[ks], bfr, acc);
    }
    int col = (cf << 4) + (l & 15);
    float bias = b2[col];
#pragma unroll
    for (int j = 0; j < 4; ++j) {
      float h = fmaxf(acc[j] + bias, 0.f);
      int row = ((l >> 4) << 2) + j;
      int byte = (row * 512 + col * 2) ^ ((row & 7) << 4);
      *(unsigned short*)((char*)h2 + byte) = f2bf(h);
    }
  }

  // ---- layer 3: z = h2 @ W3 + b3 (kept in regs) ----
  short8 a3[8];
  {
    int row = l & 15, sw = (row & 7) << 4;
#pragma unroll
    for (int ks = 0; ks < 8; ++ks)
      a3[ks] = *(short8*)((char*)h2 + ((row * 512 + ks * 64 + ((l >> 4) << 4)) ^ sw));
  }
  const unsigned short* W3f = ws16 + OFF_W3F / 2;
  floatx4 z[16];
#pragma unroll
  for (int cf = 0; cf < 16; ++cf) {
    floatx4 acc = {0.f, 0.f, 0.f, 0.f};
#pragma unroll
    for (int ks = 0; ks < 8; ++ks) {
      short8 bfr = *(const short8*)(W3f + ((size_t)(cf * 8 + ks) * 64 + l) * 8);
      acc = MFMA16(a3[ks], bfr, acc);
    }
    float bias = b3[(cf << 4) + (l & 15)];
#pragma unroll
    for (int j = 0; j < 4; ++j) acc[j] += bias;
    z[cf] = acc;
  }

  // ---- LayerNorm: stats per row via in-reg + 16-lane shfl_xor reduce ----
  float mu[4], rstd[4];
#pragma unroll
  for (int j = 0; j < 4; ++j) {
    float s = 0.f, q = 0.f;
#pragma unroll
    for (int cf = 0; cf < 16; ++cf) { float v = z[cf][j]; s += v; q = fmaf(v, v, q); }
#pragma unroll
    for (int m = 1; m < 16; m <<= 1) { s += __shfl_xor(s, m, 64); q += __shfl_xor(q, m, 64); }
    float mm = s * 0.00390625f;
    float var = q * 0.00390625f - mm * mm;  // biased var (matches torch LN)
    mu[j] = mm;
    rstd[j] = rsqrtf(var + 1e-5f);
  }
  float nacc[4] = {0.f, 0.f, 0.f, 0.f};
#pragma unroll
  for (int cf = 0; cf < 16; ++cf) {
    int col = (cf << 4) + (l & 15);
    float g = gamma[col], be = beta[col];
#pragma unroll
    for (int j = 0; j < 4; ++j) {
      float y = (z[cf][j] - mu[j]) * rstd[j] * g + be;
      nacc[j] = fmaf(y, y, nacc[j]);
      int row = ((l >> 4) << 2) + j;
      if (is_src) out_src[(size_t)(row0 + row) * 256 + col] = y;
      int byte = (row * 512 + col * 2) ^ ((row & 7) << 4);
      *(unsigned short*)((char*)h1 + byte) = f2bf(y);  // reuse h1 as transpose buf
    }
  }
  // row norms^2
#pragma unroll
  for (int j = 0; j < 4; ++j) {
    float q = nacc[j];
#pragma unroll
    for (int m = 1; m < 16; m <<= 1) q += __shfl_xor(q, m, 64);
    if ((l & 15) == 0) nrm[row0 + ((l >> 4) << 2) + j] = q;
  }
  // bf16 frag-linear store (A/B-frag ready for dist_kernel)
  {
    int row = l & 15, sw = (row & 7) << 4;
    int tile = row0 >> 4;
#pragma unroll
    for (int ks = 0; ks < 8; ++ks) {
      short8 yv = *(short8*)((char*)h1 + ((row * 512 + ks * 64 + ((l >> 4) << 4)) ^ sw));
      *(short8*)(fragout + ((size_t)(tile * 8 + ks) * 64 + l) * 8) = yv;
    }
  }
}

// ---------------------------------------------------------------------------
// dist: block = 64 src rows, 8 waves (rg = w>>2 row half, cg = w&3 col quarter)
//       wave tile 32 rows x 64 cols, 64 iters x 256 tgt cols. A-frags resident.
// ---------------------------------------------------------------------------
__global__ __launch_bounds__(512) void dist_kernel(
    const unsigned short* __restrict__ srcf, const unsigned short* __restrict__ tgtf,
    const float* __restrict__ s2, const float* __restrict__ t2,
    float* __restrict__ eout) {
  __shared__ float mb[64][4][3];
  const int tid = threadIdx.x, w = tid >> 6, l = tid & 63;
  const int rg = w >> 2, cg = w & 3;
  const int blk = blockIdx.x;
  const int R0 = (blk << 6) + (rg << 5);

  short8 a[2][8];
#pragma unroll
  for (int rf = 0; rf < 2; ++rf)
#pragma unroll
    for (int ks = 0; ks < 8; ++ks)
      a[rf][ks] = *(const short8*)(srcf + (((size_t)((R0 >> 4) + rf) * 8 + ks) * 64 + l) * 8);

  float t3[2][4][3];
#pragma unroll
  for (int rf = 0; rf < 2; ++rf)
#pragma unroll
    for (int j = 0; j < 4; ++j) { t3[rf][j][0] = 1e30f; t3[rf][j][1] = 1e30f; t3[rf][j][2] = 1e30f; }

  for (int it = 0; it < 64; ++it) {
    int colbase = it * 256 + (cg << 6);
#pragma unroll
    for (int cf = 0; cf < 4; ++cf) {
      int Tc = (colbase >> 4) + cf;
      float t2c = t2[colbase + (cf << 4) + (l & 15)];
      short8 bfr[8];
#pragma unroll
      for (int ks = 0; ks < 8; ++ks)
        bfr[ks] = *(const short8*)(tgtf + (((size_t)Tc * 8 + ks) * 64 + l) * 8);
      floatx4 acc0 = {0.f, 0.f, 0.f, 0.f}, acc1 = {0.f, 0.f, 0.f, 0.f};
#pragma unroll
      for (int ks = 0; ks < 8; ++ks) {
        acc0 = MFMA16(a[0][ks], bfr[ks], acc0);
        acc1 = MFMA16(a[1][ks], bfr[ks], acc1);
      }
#pragma unroll
      for (int j = 0; j < 4; ++j) {
        ins3(t3[0][j][0], t3[0][j][1], t3[0][j][2], fmaf(-2.f, acc0[j], t2c));
        ins3(t3[1][j][0], t3[1][j][1], t3[1][j][2], fmaf(-2.f, acc1[j], t2c));
      }
    }
  }

  // merge across the 16 column-lanes (butterfly)
#pragma unroll
  for (int rf = 0; rf < 2; ++rf)
#pragma unroll
    for (int j = 0; j < 4; ++j)
#pragma unroll
      for (int m = 1; m < 16; m <<= 1) {
        float o0 = __shfl_xor(t3[rf][j][0], m, 64);
        float o1 = __shfl_xor(t3[rf][j][1], m, 64);
        float o2 = __shfl_xor(t3[rf][j][2], m, 64);
        ins3(t3[rf][j][0], t3[rf][j][1], t3[rf][j][2], o0);
        ins3(t3[rf][j][0], t3[rf][j][1], t3[rf][j][2], o1);
        ins3(t3[rf][j][0], t3[rf][j][1], t3[rf][j][2], o2);
      }
  if ((l & 15) == 0) {
    int q = l >> 4;
#pragma unroll
    for (int rf = 0; rf < 2; ++rf)
#pragma unroll
      for (int j = 0; j < 4; ++j) {
        int row = (rg << 5) + (rf << 4) + (q << 2) + j;
        mb[row][cg][0] = t3[rf][j][0];
        mb[row][cg][1] = t3[rf][j][1];
        mb[row][cg][2] = t3[rf][j][2];
      }
  }
  __syncthreads();
  if (tid < 64) {
    float u0 = mb[tid][0][0], u1 = mb[tid][0][1], u2 = mb[tid][0][2];
#pragma unroll
    for (int c = 1; c < 4; ++c) {
      ins3(u0, u1, u2, mb[tid][c][0]);
      ins3(u0, u1, u2, mb[tid][c][1]);
      ins3(u0, u1, u2, mb[tid][c][2]);
    }
    float sv = s2[(blk << 6) + tid];
    float d0 = sqrtf(fmaxf(sv + u0, 0.f));
    float d1 = sqrtf(fmaxf(sv + u1, 0.f));
    float d2 = sqrtf(fmaxf(sv + u2, 0.f));
    eout[(blk << 6) + tid] = (d0 + d1 + d2) * 0.5f;  // faithful /(k-1)=2
  }
}

extern "C" void kernel_launch(void* const* d_in, const int* in_sizes, int n_in,
                              void* d_out, int out_size, void* d_ws, size_t ws_size,
                              hipStream_t stream) {
  const float* xsrc = (const float*)d_in[0];
  const float* xtgt = (const float*)d_in[1];
  const float* W1 = (const float*)d_in[2];
  const float* b1 = (const float*)d_in[3];
  const float* W2 = (const float*)d_in[4];
  const float* b2 = (const float*)d_in[5];
  const float* W3 = (const float*)d_in[6];
  const float* b3 = (const float*)d_in[7];
  const float* gm = (const float*)d_in[8];
  const float* bt = (const float*)d_in[9];
  float* out = (float*)d_out;
  unsigned short* ws16 = (unsigned short*)d_ws;

  prep_weights<<<80, 256, 0, stream>>>(W1, W2, W3, ws16);
  encode_kernel<<<512, 256, 0, stream>>>(xsrc, xtgt, b1, b2, b3, gm, bt, out, ws16);
  dist_kernel<<<256, 512, 0, stream>>>(ws16 + OFF_SRCF / 2, ws16 + OFF_TGTF / 2,
                                       (const float*)((char*)d_ws + OFF_S2),
                                       (const float*)((char*)d_ws + OFF_T2),
                                       out + 4194304);
}

// Round 2
// 285.866 us; speedup vs baseline: 1.4488x; 1.4488x over previous
//
#include <hip/hip_runtime.h>
#include <math.h>

// ============================================================================
// re3: MLP-encode (3 layers + LayerNorm) of src/tgt, then fused
//      all-pairs-L2-distance + top-3-smallest + sum/2 ("state entropy").
//
// Round-2 change: dist_kernel rewritten for operand reuse.
//   - A (src) resident in VGPRs: 64 rows/wave (rf=4) -> 4 MFMA per B b128.
//   - BM=512 rows/block (8 waves), tgt columns split 8-way across blocks;
//     split == blockIdx.x & 7 == XCD id under round-robin dispatch, so each
//     XCD's 1 MB B-slice stays L2-resident.
//   - B staged per 64-col tile into LDS (32 KB x2, double-buffered) with
//     global_load_lds(16); 2-phase schedule: stage(next) -> compute(cur)
//     -> __syncthreads. Linear LDS, lane-contiguous reads (no conflicts).
//   - Partial top-3 per (row, split) -> ws; merge_kernel folds 8 splits.
// ============================================================================

typedef __attribute__((ext_vector_type(8))) short short8;
typedef __attribute__((ext_vector_type(4))) float floatx4;
typedef __attribute__((ext_vector_type(4))) unsigned short ushortx4;

#define MFMA16(a, b, c) __builtin_amdgcn_mfma_f32_16x16x32_bf16((a), (b), (c), 0, 0, 0)

// ---- ws layout (bytes) ----
static const size_t OFF_W1F  = 0;                       //  64 KB
static const size_t OFF_W2F  = 65536;                   // 128 KB
static const size_t OFF_W3F  = 196608;                  // 128 KB
static const size_t OFF_SRCF = 327680;                  //   8 MB frag-linear src
static const size_t OFF_TGTF = 327680 + 8388608;        //   8 MB frag-linear tgt
static const size_t OFF_S2   = 327680 + 2 * 8388608;    //  64 KB |src row|^2
static const size_t OFF_T2   = OFF_S2 + 65536;          //  64 KB |tgt row|^2
static const size_t OFF_P    = OFF_T2 + 65536;          // 1.5 MB partial top-3

__device__ __forceinline__ unsigned short f2bf(float f) {
  unsigned int u = __float_as_uint(f);
  return (unsigned short)((u + 0x7FFFu + ((u >> 16) & 1u)) >> 16);  // RNE
}

// keep 3 smallest seen: t0<=t1<=t2, insert v  (1 min + 2 fmed3)
__device__ __forceinline__ void ins3(float& t0, float& t1, float& t2, float v) {
  float n0 = fminf(t0, v);
  float n1 = __builtin_amdgcn_fmed3f(t0, t1, v);
  float n2 = __builtin_amdgcn_fmed3f(t1, t2, v);
  t0 = n0; t1 = n1; t2 = n2;
}

// global -> LDS direct copy, 16 B per lane. lds dest = uniform base + lane*16.
__device__ __forceinline__ void gload16(const void* g, void* l) {
  __builtin_amdgcn_global_load_lds(
      (const __attribute__((address_space(1))) unsigned int*)(unsigned long long)(uintptr_t)g,
      (__attribute__((address_space(3))) unsigned int*)(unsigned int)(uintptr_t)l, 16, 0, 0);
}

// ---------------------------------------------------------------------------
// prep: W[k][c] fp32 -> bf16 frag-linear: elem j of frag ((cf*KS+ks)*64+l)
//       = W[ks*32 + (l>>4)*8 + j][cf*16 + (l&15)]
// ---------------------------------------------------------------------------
__global__ void prep_weights(const float* __restrict__ W1, const float* __restrict__ W2,
                             const float* __restrict__ W3, unsigned short* __restrict__ ws16) {
  int t = blockIdx.x * 256 + threadIdx.x;  // 20480 total
  const float* W;
  unsigned short* dst;
  int f, ksbits;
  if (t < 4096)       { W = W1; dst = ws16 + OFF_W1F / 2; f = t;         ksbits = 2; }
  else if (t < 12288) { W = W2; dst = ws16 + OFF_W2F / 2; f = t - 4096;  ksbits = 3; }
  else                { W = W3; dst = ws16 + OFF_W3F / 2; f = t - 12288; ksbits = 3; }
  int l  = f & 63;
  int fk = f >> 6;
  int ks = fk & ((1 << ksbits) - 1);
  int cf = fk >> ksbits;
  int k0 = ks * 32 + ((l >> 4) << 3);
  int c  = (cf << 4) + (l & 15);
  short8 v;
#pragma unroll
  for (int j = 0; j < 8; ++j) v[j] = (short)f2bf(W[(size_t)(k0 + j) * 256 + c]);
  *(short8*)(dst + (size_t)f * 8) = v;
}

// ---------------------------------------------------------------------------
// encode: unchanged from round 1 (verified). blocks 0..255 = src, 256..511 =
//         tgt; 4 independent 16-row waves; XOR-swizzled LDS staging.
// ---------------------------------------------------------------------------
__global__ __launch_bounds__(256) void encode_kernel(
    const float* __restrict__ xsrc, const float* __restrict__ xtgt,
    const float* __restrict__ b1, const float* __restrict__ b2, const float* __restrict__ b3,
    const float* __restrict__ gamma, const float* __restrict__ beta,
    float* __restrict__ out_src, unsigned short* __restrict__ ws16) {
  __shared__ unsigned short lds[4][10240];  // 80 KB
  const int tid = threadIdx.x, w = tid >> 6, l = tid & 63;
  const int blk = blockIdx.x;
  const bool is_src = blk < 256;
  const int row0 = ((blk & 255) << 6) + (w << 4);
  const float* __restrict__ X = is_src ? xsrc : xtgt;
  unsigned short* __restrict__ fragout = ws16 + (is_src ? OFF_SRCF / 2 : OFF_TGTF / 2);
  float* __restrict__ nrm = (float*)(ws16 + (is_src ? OFF_S2 / 2 : OFF_T2 / 2));

  unsigned short* xb = &lds[w][0];
  unsigned short* h1 = &lds[w][2048];
  unsigned short* h2 = &lds[w][6144];

#pragma unroll
  for (int i = 0; i < 8; ++i) {
    int idx = i * 64 + l;
    int r = idx >> 5, c4 = idx & 31;
    floatx4 xv = *(const floatx4*)(X + (size_t)(row0 + r) * 128 + c4 * 4);
    ushortx4 bv;
#pragma unroll
    for (int j = 0; j < 4; ++j) bv[j] = f2bf(xv[j]);
    int byte = (r * 256 + c4 * 8) ^ ((r & 7) << 4);
    *(ushortx4*)((char*)xb + byte) = bv;
  }

  short8 a1[4];
  {
    int row = l & 15, sw = (row & 7) << 4;
#pragma unroll
    for (int ks = 0; ks < 4; ++ks)
      a1[ks] = *(short8*)((char*)xb + ((row * 256 + ks * 64 + ((l >> 4) << 4)) ^ sw));
  }
  const unsigned short* W1f = ws16 + OFF_W1F / 2;
#pragma unroll
  for (int cf = 0; cf < 16; ++cf) {
    floatx4 acc = {0.f, 0.f, 0.f, 0.f};
#pragma unroll
    for (int ks = 0; ks < 4; ++ks) {
      short8 bfr = *(const short8*)(W1f + ((size_t)(cf * 4 + ks) * 64 + l) * 8);
      acc = MFMA16(a1[ks], bfr, acc);
    }
    int col = (cf << 4) + (l & 15);
    float bias = b1[col];
#pragma unroll
    for (int j = 0; j < 4; ++j) {
      float h = fmaxf(acc[j] + bias, 0.f);
      int row = ((l >> 4) << 2) + j;
      int byte = (row * 512 + col * 2) ^ ((row & 7) << 4);
      *(unsigned short*)((char*)h1 + byte) = f2bf(h);
    }
  }

  short8 a2[8];
  {
    int row = l & 15, sw = (row & 7) << 4;
#pragma unroll
    for (int ks = 0; ks < 8; ++ks)
      a2[ks] = *(short8*)((char*)h1 + ((row * 512 + ks * 64 + ((l >> 4) << 4)) ^ sw));
  }
  const unsigned short* W2f = ws16 + OFF_W2F / 2;
#pragma unroll
  for (int cf = 0; cf < 16; ++cf) {
    floatx4 acc = {0.f, 0.f, 0.f, 0.f};
#pragma unroll
    for (int ks = 0; ks < 8; ++ks) {
      short8 bfr = *(const short8*)(W2f + ((size_t)(cf * 8 + ks) * 64 + l) * 8);
      acc = MFMA16(a2[ks], bfr, acc);
    }
    int col = (cf << 4) + (l & 15);
    float bias = b2[col];
#pragma unroll
    for (int j = 0; j < 4; ++j) {
      float h = fmaxf(acc[j] + bias, 0.f);
      int row = ((l >> 4) << 2) + j;
      int byte = (row * 512 + col * 2) ^ ((row & 7) << 4);
      *(unsigned short*)((char*)h2 + byte) = f2bf(h);
    }
  }

  short8 a3[8];
  {
    int row = l & 15, sw = (row & 7) << 4;
#pragma unroll
    for (int ks = 0; ks < 8; ++ks)
      a3[ks] = *(short8*)((char*)h2 + ((row * 512 + ks * 64 + ((l >> 4) << 4)) ^ sw));
  }
  const unsigned short* W3f = ws16 + OFF_W3F / 2;
  floatx4 z[16];
#pragma unroll
  for (int cf = 0; cf < 16; ++cf) {
    floatx4 acc = {0.f, 0.f, 0.f, 0.f};
#pragma unroll
    for (int ks = 0; ks < 8; ++ks) {
      short8 bfr = *(const short8*)(W3f + ((size_t)(cf * 8 + ks) * 64 + l) * 8);
      acc = MFMA16(a3[ks], bfr, acc);
    }
    float bias = b3[(cf << 4) + (l & 15)];
#pragma unroll
    for (int j = 0; j < 4; ++j) acc[j] += bias;
    z[cf] = acc;
  }

  float mu[4], rstd[4];
#pragma unroll
  for (int j = 0; j < 4; ++j) {
    float s = 0.f, q = 0.f;
#pragma unroll
    for (int cf = 0; cf < 16; ++cf) { float v = z[cf][j]; s += v; q = fmaf(v, v, q); }
#pragma unroll
    for (int m = 1; m < 16; m <<= 1) { s += __shfl_xor(s, m, 64); q += __shfl_xor(q, m, 64); }
    float mm = s * 0.00390625f;
    float var = q * 0.00390625f - mm * mm;
    mu[j] = mm;
    rstd[j] = rsqrtf(var + 1e-5f);
  }
  float nacc[4] = {0.f, 0.f, 0.f, 0.f};
#pragma unroll
  for (int cf = 0; cf < 16; ++cf) {
    int col = (cf << 4) + (l & 15);
    float g = gamma[col], be = beta[col];
#pragma unroll
    for (int j = 0; j < 4; ++j) {
      float y = (z[cf][j] - mu[j]) * rstd[j] * g + be;
      nacc[j] = fmaf(y, y, nacc[j]);
      int row = ((l >> 4) << 2) + j;
      if (is_src) out_src[(size_t)(row0 + row) * 256 + col] = y;
      int byte = (row * 512 + col * 2) ^ ((row & 7) << 4);
      *(unsigned short*)((char*)h1 + byte) = f2bf(y);
    }
  }
#pragma unroll
  for (int j = 0; j < 4; ++j) {
    float q = nacc[j];
#pragma unroll
    for (int m = 1; m < 16; m <<= 1) q += __shfl_xor(q, m, 64);
    if ((l & 15) == 0) nrm[row0 + ((l >> 4) << 2) + j] = q;
  }
  {
    int row = l & 15, sw = (row & 7) << 4;
    int tile = row0 >> 4;
#pragma unroll
    for (int ks = 0; ks < 8; ++ks) {
      short8 yv = *(short8*)((char*)h1 + ((row * 512 + ks * 64 + ((l >> 4) << 4)) ^ sw));
      *(short8*)(fragout + ((size_t)(tile * 8 + ks) * 64 + l) * 8) = yv;
    }
  }
}

// ---------------------------------------------------------------------------
// dist: grid 256 = 32 row-tiles x 8 col-splits (split = blk&7 = XCD).
//       Block: 512 rows, 8 waves x 64 rows (rf=4, A resident 128 VGPR).
//       Loop 32 tiles of 64 cols: LDS double-buffer staged by global_load_lds.
//       Emits per-(row,split) top-3 of v = |t|^2 - 2 s.t  to ws.
// ---------------------------------------------------------------------------
__global__ __launch_bounds__(512, 2) void dist_kernel(
    const unsigned short* __restrict__ srcf, const unsigned short* __restrict__ tgtf,
    const float* __restrict__ t2, float* __restrict__ part) {
  __shared__ unsigned short buf[2][16384];  // 2 x 32 KB
  const int tid = threadIdx.x, w = tid >> 6, l = tid & 63;
  const int blk = blockIdx.x;
  const int split = blk & 7;
  const int rtile = blk >> 3;                 // 0..31
  const int R0 = rtile * 512 + w * 64;        // this wave's first row
  const int C0 = split * 2048;                // this block's first col

  // resident A fragments: 4 row-tiles x 8 k-slices (16 B each)
  short8 a[4][8];
#pragma unroll
  for (int rf = 0; rf < 4; ++rf)
#pragma unroll
    for (int ks = 0; ks < 8; ++ks)
      a[rf][ks] = *(const short8*)(srcf + (((size_t)(R0 / 16 + rf) * 8 + ks) * 64 + l) * 8);

  float t3[4][4][3];
#pragma unroll
  for (int rf = 0; rf < 4; ++rf)
#pragma unroll
    for (int j = 0; j < 4; ++j) { t3[rf][j][0] = 1e30f; t3[rf][j][1] = 1e30f; t3[rf][j][2] = 1e30f; }

  // stage tile t (64 cols = 32 KB = 32 chunks of 1 KB); wave w stages chunks w*4..w*4+3
  const unsigned short* gb0 = tgtf + (size_t)(C0 / 16) * 4096;  // frag base of this split
#define STAGE(bsel, t)                                                        \
  {                                                                           \
    const unsigned short* gb = gb0 + (size_t)(t) * 16384;                     \
    _Pragma("unroll") for (int i = 0; i < 4; ++i) {                           \
      int chunk = w * 4 + i;                                                  \
      gload16(gb + chunk * 512 + l * 8, &buf[bsel][chunk * 512]);             \
    }                                                                         \
  }

  STAGE(0, 0);
  __syncthreads();

  for (int t = 0; t < 32; ++t) {
    int cur = t & 1;
    if (t < 31) STAGE(cur ^ 1, t + 1);
    int colbase = C0 + t * 64;
#pragma unroll
    for (int cf = 0; cf < 4; ++cf) {
      float t2c = t2[colbase + cf * 16 + (l & 15)];
      floatx4 acc[4];
#pragma unroll
      for (int rf = 0; rf < 4; ++rf) acc[rf] = (floatx4){0.f, 0.f, 0.f, 0.f};
#pragma unroll
      for (int ks = 0; ks < 8; ++ks) {
        short8 bfr = *(const short8*)(&buf[cur][(cf * 8 + ks) * 512 + l * 8]);
#pragma unroll
        for (int rf = 0; rf < 4; ++rf) acc[rf] = MFMA16(a[rf][ks], bfr, acc[rf]);
      }
#pragma unroll
      for (int rf = 0; rf < 4; ++rf)
#pragma unroll
        for (int j = 0; j < 4; ++j)
          ins3(t3[rf][j][0], t3[rf][j][1], t3[rf][j][2], fmaf(-2.f, acc[rf][j], t2c));
    }
    __syncthreads();  // drains vmcnt: stage of t+1 complete; all reads of cur done
  }
#undef STAGE

  // merge across the 16 column-lanes (butterfly; rows (l>>4) preserved)
#pragma unroll
  for (int rf = 0; rf < 4; ++rf)
#pragma unroll
    for (int j = 0; j < 4; ++j)
#pragma unroll
      for (int m = 1; m < 16; m <<= 1) {
        float o0 = __shfl_xor(t3[rf][j][0], m, 64);
        float o1 = __shfl_xor(t3[rf][j][1], m, 64);
        float o2 = __shfl_xor(t3[rf][j][2], m, 64);
        ins3(t3[rf][j][0], t3[rf][j][1], t3[rf][j][2], o0);
        ins3(t3[rf][j][0], t3[rf][j][1], t3[rf][j][2], o1);
        ins3(t3[rf][j][0], t3[rf][j][1], t3[rf][j][2], o2);
      }
  if ((l & 15) == 0) {
    int q = l >> 4;
#pragma unroll
    for (int rf = 0; rf < 4; ++rf)
#pragma unroll
      for (int j = 0; j < 4; ++j) {
        int row = R0 + rf * 16 + q * 4 + j;
        float* p = part + ((size_t)row * 8 + split) * 3;
        p[0] = t3[rf][j][0];
        p[1] = t3[rf][j][1];
        p[2] = t3[rf][j][2];
      }
  }
}

// ---------------------------------------------------------------------------
// merge: per row fold 8 splits x 3 candidates, add |s|^2, sqrt, entropy.
// ---------------------------------------------------------------------------
__global__ void merge_kernel(const float* __restrict__ part, const float* __restrict__ s2,
                             float* __restrict__ eout) {
  int r = blockIdx.x * 256 + threadIdx.x;  // 16384
  const float* p = part + (size_t)r * 24;
  float u0 = 1e30f, u1 = 1e30f, u2 = 1e30f;
#pragma unroll
  for (int i = 0; i < 24; ++i) ins3(u0, u1, u2, p[i]);
  float sv = s2[r];
  float d0 = sqrtf(fmaxf(sv + u0, 0.f));
  float d1 = sqrtf(fmaxf(sv + u1, 0.f));
  float d2 = sqrtf(fmaxf(sv + u2, 0.f));
  eout[r] = (d0 + d1 + d2) * 0.5f;
}

extern "C" void kernel_launch(void* const* d_in, const int* in_sizes, int n_in,
                              void* d_out, int out_size, void* d_ws, size_t ws_size,
                              hipStream_t stream) {
  const float* xsrc = (const float*)d_in[0];
  const float* xtgt = (const float*)d_in[1];
  const float* W1 = (const float*)d_in[2];
  const float* b1 = (const float*)d_in[3];
  const float* W2 = (const float*)d_in[4];
  const float* b2 = (const float*)d_in[5];
  const float* W3 = (const float*)d_in[6];
  const float* b3 = (const float*)d_in[7];
  const float* gm = (const float*)d_in[8];
  const float* bt = (const float*)d_in[9];
  float* out = (float*)d_out;
  unsigned short* ws16 = (unsigned short*)d_ws;

  prep_weights<<<80, 256, 0, stream>>>(W1, W2, W3, ws16);
  encode_kernel<<<512, 256, 0, stream>>>(xsrc, xtgt, b1, b2, b3, gm, bt, out, ws16);
  dist_kernel<<<256, 512, 0, stream>>>(ws16 + OFF_SRCF / 2, ws16 + OFF_TGTF / 2,
                                       (const float*)((char*)d_ws + OFF_T2),
                                       (float*)((char*)d_ws + OFF_P));
  merge_kernel<<<64, 256, 0, stream>>>((const float*)((char*)d_ws + OFF_P),
                                       (const float*)((char*)d_ws + OFF_S2),
                                       out + 4194304);
}

// Round 3
// 217.320 us; speedup vs baseline: 1.9058x; 1.3154x over previous
//
#include <hip/hip_runtime.h>
#include <math.h>

// ============================================================================
// re3: MLP-encode (3 layers + LayerNorm) of src/tgt, then fused
//      all-pairs-L2-distance + top-3-smallest + sum/2 ("state entropy").
//
// Round-3 change: encode_kernel rewritten LDS-free / barrier-free.
//   Transposed compute: layer_i^T = relu(W_i^T @ h_{i-1}^T) via
//   MFMA(A = W-frag [prep layout is exactly the A-frag], B = data-frag).
//   D-layout keeps each data row lane-local (col = l&15); the next layer's
//   B-frag is built by a pure-register exchange: shfl_xor(16) -> pair quads
//   -> shfl_xor(32) -> per-group select. LN stats = 2 shuffles. The final
//   exchanged y IS the frag-linear layout dist_kernel consumes.
// dist_kernel / prep_weights / merge_kernel unchanged from round 2.
// ============================================================================

typedef __attribute__((ext_vector_type(8))) short short8;
typedef __attribute__((ext_vector_type(4))) float floatx4;

#define MFMA16(a, b, c) __builtin_amdgcn_mfma_f32_16x16x32_bf16((a), (b), (c), 0, 0, 0)

// ---- ws layout (bytes) ----
static const size_t OFF_W1F  = 0;                       //  64 KB
static const size_t OFF_W2F  = 65536;                   // 128 KB
static const size_t OFF_W3F  = 196608;                  // 128 KB
static const size_t OFF_SRCF = 327680;                  //   8 MB frag-linear src
static const size_t OFF_TGTF = 327680 + 8388608;        //   8 MB frag-linear tgt
static const size_t OFF_S2   = 327680 + 2 * 8388608;    //  64 KB |src row|^2
static const size_t OFF_T2   = OFF_S2 + 65536;          //  64 KB |tgt row|^2
static const size_t OFF_P    = OFF_T2 + 65536;          // 1.5 MB partial top-3

__device__ __forceinline__ unsigned short f2bf(float f) {
  unsigned int u = __float_as_uint(f);
  return (unsigned short)((u + 0x7FFFu + ((u >> 16) & 1u)) >> 16);  // RNE
}

__device__ __forceinline__ unsigned int pkbf(float lo, float hi) {
  unsigned int r;
  asm("v_cvt_pk_bf16_f32 %0, %1, %2" : "=v"(r) : "v"(lo), "v"(hi));
  return r;
}

// keep 3 smallest seen: t0<=t1<=t2, insert v  (1 min + 2 fmed3)
__device__ __forceinline__ void ins3(float& t0, float& t1, float& t2, float v) {
  float n0 = fminf(t0, v);
  float n1 = __builtin_amdgcn_fmed3f(t0, t1, v);
  float n2 = __builtin_amdgcn_fmed3f(t1, t2, v);
  t0 = n0; t1 = n1; t2 = n2;
}

// global -> LDS direct copy, 16 B per lane.
__device__ __forceinline__ void gload16(const void* g, void* l) {
  __builtin_amdgcn_global_load_lds(
      (const __attribute__((address_space(1))) unsigned int*)(unsigned long long)(uintptr_t)g,
      (__attribute__((address_space(3))) unsigned int*)(unsigned int)(uintptr_t)l, 16, 0, 0);
}

__device__ __forceinline__ unsigned int sxor(unsigned int v, int m) {
  return (unsigned int)__shfl_xor((int)v, m, 64);
}

// ---------------------------------------------------------------------------
// exchange: D-layout packed words -> B-frags for the next layer (K=256).
//   input : p0[t], p1[t] for 16 tiles: p0[t]=bf16x2 of channels t*16+g*4+{0,1}
//           (p1: +{2,3}), all for data row dr = l&15.
//   output: frag[ks] elem j = val[dr][ks*32 + g*8 + j], j=0..7.
// Verified mapping (4 concrete (g,ks) cases checked by hand).
// ---------------------------------------------------------------------------
__device__ __forceinline__ void exchange8(const unsigned int* p0, const unsigned int* p1,
                                          short8* frag, int g) {
  const bool go = (g & 1), gh = (g >> 1);
#pragma unroll
  for (int ks = 0; ks < 8; ++ks) {
    unsigned int a_o = p0[2 * ks], b_o = p1[2 * ks];
    unsigned int c_o = p0[2 * ks + 1], d_o = p1[2 * ks + 1];
    unsigned int a_n = sxor(a_o, 16), b_n = sxor(b_o, 16);
    unsigned int c_n = sxor(c_o, 16), d_n = sxor(d_o, 16);
    // canonical pair quads: QAB = [A_even,B_even,A_odd,B_odd] of tile 2ks,
    //                       QCD = same of tile 2ks+1
    unsigned int qab0 = go ? a_n : a_o, qab1 = go ? b_n : b_o;
    unsigned int qab2 = go ? a_o : a_n, qab3 = go ? b_o : b_n;
    unsigned int qcd0 = go ? c_n : c_o, qcd1 = go ? d_n : d_o;
    unsigned int qcd2 = go ? c_o : c_n, qcd3 = go ? d_o : d_n;
    // cross-pair swap: send QCD from lower pair, QAB from upper pair
    unsigned int s0 = gh ? qab0 : qcd0, s1 = gh ? qab1 : qcd1;
    unsigned int s2 = gh ? qab2 : qcd2, s3 = gh ? qab3 : qcd3;
    unsigned int r0 = sxor(s0, 32), r1 = sxor(s1, 32);
    unsigned int r2 = sxor(s2, 32), r3 = sxor(s3, 32);
    union { unsigned int u[4]; short8 s; } cv;
    cv.u[0] = (g == 0) ? qab0 : (g == 3) ? qcd0 : r0;
    cv.u[1] = (g == 0) ? qab1 : (g == 3) ? qcd1 : r1;
    cv.u[2] = (g == 0) ? qab2 : (g == 3) ? qcd2 : r2;
    cv.u[3] = (g == 0) ? qab3 : (g == 3) ? qcd3 : r3;
    frag[ks] = cv.s;
  }
}

// ---------------------------------------------------------------------------
// prep: W[k][c] fp32 -> bf16 frag-linear: elem j of frag ((cf*KS+ks)*64+l)
//       = W[ks*32 + (l>>4)*8 + j][cf*16 + (l&15)]   (== A-frag of W^T)
// ---------------------------------------------------------------------------
__global__ void prep_weights(const float* __restrict__ W1, const float* __restrict__ W2,
                             const float* __restrict__ W3, unsigned short* __restrict__ ws16) {
  int t = blockIdx.x * 256 + threadIdx.x;  // 20480 total
  const float* W;
  unsigned short* dst;
  int f, ksbits;
  if (t < 4096)       { W = W1; dst = ws16 + OFF_W1F / 2; f = t;         ksbits = 2; }
  else if (t < 12288) { W = W2; dst = ws16 + OFF_W2F / 2; f = t - 4096;  ksbits = 3; }
  else                { W = W3; dst = ws16 + OFF_W3F / 2; f = t - 12288; ksbits = 3; }
  int l  = f & 63;
  int fk = f >> 6;
  int ks = fk & ((1 << ksbits) - 1);
  int cf = fk >> ksbits;
  int k0 = ks * 32 + ((l >> 4) << 3);
  int c  = (cf << 4) + (l & 15);
  short8 v;
#pragma unroll
  for (int j = 0; j < 8; ++j) v[j] = (short)f2bf(W[(size_t)(k0 + j) * 256 + c]);
  *(short8*)(dst + (size_t)f * 8) = v;
}

// ---------------------------------------------------------------------------
// encode: LDS-free. blocks 0..255 = src, 256..511 = tgt; 4 independent waves
//         x 16 rows. All inter-layer transposes in-register (exchange8).
// ---------------------------------------------------------------------------
__global__ __launch_bounds__(256, 2) void encode_kernel(
    const float* __restrict__ xsrc, const float* __restrict__ xtgt,
    const float* __restrict__ b1, const float* __restrict__ b2, const float* __restrict__ b3,
    const float* __restrict__ gamma, const float* __restrict__ beta,
    float* __restrict__ out_src, unsigned short* __restrict__ ws16) {
  const int tid = threadIdx.x, w = tid >> 6, l = tid & 63;
  const int dr = l & 15, g = l >> 4;
  const int blk = blockIdx.x;
  const bool is_src = blk < 256;
  const int row0 = ((blk & 255) << 6) + (w << 4);
  const int row = row0 + dr;  // this lane's data row
  const float* __restrict__ X = is_src ? xsrc : xtgt;
  unsigned short* __restrict__ fragout = ws16 + (is_src ? OFF_SRCF / 2 : OFF_TGTF / 2);
  float* __restrict__ nrm = (float*)(ws16 + (is_src ? OFF_S2 / 2 : OFF_T2 / 2));
  const unsigned short* W1f = ws16 + OFF_W1F / 2;
  const unsigned short* W2f = ws16 + OFF_W2F / 2;
  const unsigned short* W3f = ws16 + OFF_W3F / 2;

  // ---- x as B-frags straight from global (K=128 -> 4 frags) ----
  short8 xf[4];
  const float* xr = X + (size_t)row * 128;
#pragma unroll
  for (int ks = 0; ks < 4; ++ks) {
    floatx4 f0 = *(const floatx4*)(xr + ks * 32 + g * 8);
    floatx4 f1 = *(const floatx4*)(xr + ks * 32 + g * 8 + 4);
    union { unsigned int u[4]; short8 s; } cv;
    cv.u[0] = pkbf(f0[0], f0[1]); cv.u[1] = pkbf(f0[2], f0[3]);
    cv.u[2] = pkbf(f1[0], f1[1]); cv.u[3] = pkbf(f1[2], f1[3]);
    xf[ks] = cv.s;
  }

  unsigned int p0[16], p1[16];
  short8 hf[8];

  // ---- layer 1: h1^T = relu(W1^T @ x^T + b1) ----
#pragma unroll
  for (int cf = 0; cf < 16; ++cf) {
    floatx4 acc = {0.f, 0.f, 0.f, 0.f};
#pragma unroll
    for (int ks = 0; ks < 4; ++ks) {
      short8 wf = *(const short8*)(W1f + ((size_t)(cf * 4 + ks) * 64 + l) * 8);
      acc = MFMA16(wf, xf[ks], acc);
    }
    floatx4 bv = *(const floatx4*)(b1 + cf * 16 + g * 4);
    float h0 = fmaxf(acc[0] + bv[0], 0.f), h1v = fmaxf(acc[1] + bv[1], 0.f);
    float h2v = fmaxf(acc[2] + bv[2], 0.f), h3v = fmaxf(acc[3] + bv[3], 0.f);
    p0[cf] = pkbf(h0, h1v); p1[cf] = pkbf(h2v, h3v);
  }
  exchange8(p0, p1, hf, g);

  // ---- layer 2: h2^T = relu(W2^T @ h1^T + b2), K=256 ----
#pragma unroll
  for (int cf = 0; cf < 16; ++cf) {
    floatx4 acc = {0.f, 0.f, 0.f, 0.f};
#pragma unroll
    for (int ks = 0; ks < 8; ++ks) {
      short8 wf = *(const short8*)(W2f + ((size_t)(cf * 8 + ks) * 64 + l) * 8);
      acc = MFMA16(wf, hf[ks], acc);
    }
    floatx4 bv = *(const floatx4*)(b2 + cf * 16 + g * 4);
    float h0 = fmaxf(acc[0] + bv[0], 0.f), h1v = fmaxf(acc[1] + bv[1], 0.f);
    float h2v = fmaxf(acc[2] + bv[2], 0.f), h3v = fmaxf(acc[3] + bv[3], 0.f);
    p0[cf] = pkbf(h0, h1v); p1[cf] = pkbf(h2v, h3v);
  }
  exchange8(p0, p1, hf, g);

  // ---- layer 3: z^T = W3^T @ h2^T + b3 (f32 in regs) ----
  floatx4 z[16];
#pragma unroll
  for (int cf = 0; cf < 16; ++cf) {
    floatx4 acc = {0.f, 0.f, 0.f, 0.f};
#pragma unroll
    for (int ks = 0; ks < 8; ++ks) {
      short8 wf = *(const short8*)(W3f + ((size_t)(cf * 8 + ks) * 64 + l) * 8);
      acc = MFMA16(wf, hf[ks], acc);
    }
    floatx4 bv = *(const floatx4*)(b3 + cf * 16 + g * 4);
#pragma unroll
    for (int j = 0; j < 4; ++j) acc[j] += bv[j];
    z[cf] = acc;
  }

  // ---- LayerNorm: row dr is lane-local; 2-shuffle reduction over g-lanes ----
  float s = 0.f, q = 0.f;
#pragma unroll
  for (int cf = 0; cf < 16; ++cf)
#pragma unroll
    for (int j = 0; j < 4; ++j) { float v = z[cf][j]; s += v; q = fmaf(v, v, q); }
  s += __shfl_xor(s, 16, 64); s += __shfl_xor(s, 32, 64);
  q += __shfl_xor(q, 16, 64); q += __shfl_xor(q, 32, 64);
  float mu = s * 0.00390625f;
  float var = q * 0.00390625f - mu * mu;  // biased var (torch LN)
  float rstd = rsqrtf(var + 1e-5f);

  float nacc = 0.f;
#pragma unroll
  for (int cf = 0; cf < 16; ++cf) {
    floatx4 gv = *(const floatx4*)(gamma + cf * 16 + g * 4);
    floatx4 bev = *(const floatx4*)(beta + cf * 16 + g * 4);
    float y0 = (z[cf][0] - mu) * rstd * gv[0] + bev[0];
    float y1 = (z[cf][1] - mu) * rstd * gv[1] + bev[1];
    float y2 = (z[cf][2] - mu) * rstd * gv[2] + bev[2];
    float y3 = (z[cf][3] - mu) * rstd * gv[3] + bev[3];
    nacc = fmaf(y0, y0, nacc); nacc = fmaf(y1, y1, nacc);
    nacc = fmaf(y2, y2, nacc); nacc = fmaf(y3, y3, nacc);
    p0[cf] = pkbf(y0, y1); p1[cf] = pkbf(y2, y3);
  }
  nacc += __shfl_xor(nacc, 16, 64); nacc += __shfl_xor(nacc, 32, 64);
  if (g == 0) nrm[row] = nacc;

  short8 yf[8];
  exchange8(p0, p1, yf, g);

  // ---- frag-linear store (dist's operand layout) ----
  const int tile = row0 >> 4;
#pragma unroll
  for (int ks = 0; ks < 8; ++ks)
    *(short8*)(fragout + ((size_t)(tile * 8 + ks) * 64 + l) * 8) = yf[ks];

  // ---- fp32 src output ----
  if (is_src) {
    float* orow = out_src + (size_t)row * 256;
#pragma unroll
    for (int ks = 0; ks < 8; ++ks) {
      union { short8 s; unsigned int u[4]; } cv; cv.s = yf[ks];
      floatx4 o0, o1;
      o0[0] = __uint_as_float(cv.u[0] << 16); o0[1] = __uint_as_float(cv.u[0] & 0xffff0000u);
      o0[2] = __uint_as_float(cv.u[1] << 16); o0[3] = __uint_as_float(cv.u[1] & 0xffff0000u);
      o1[0] = __uint_as_float(cv.u[2] << 16); o1[1] = __uint_as_float(cv.u[2] & 0xffff0000u);
      o1[2] = __uint_as_float(cv.u[3] << 16); o1[3] = __uint_as_float(cv.u[3] & 0xffff0000u);
      *(floatx4*)(orow + ks * 32 + g * 8) = o0;
      *(floatx4*)(orow + ks * 32 + g * 8 + 4) = o1;
    }
  }
}

// ---------------------------------------------------------------------------
// dist: unchanged from round 2. grid 256 = 32 row-tiles x 8 col-splits.
// ---------------------------------------------------------------------------
__global__ __launch_bounds__(512, 2) void dist_kernel(
    const unsigned short* __restrict__ srcf, const unsigned short* __restrict__ tgtf,
    const float* __restrict__ t2, float* __restrict__ part) {
  __shared__ unsigned short buf[2][16384];  // 2 x 32 KB
  const int tid = threadIdx.x, w = tid >> 6, l = tid & 63;
  const int blk = blockIdx.x;
  const int split = blk & 7;
  const int rtile = blk >> 3;                 // 0..31
  const int R0 = rtile * 512 + w * 64;        // this wave's first row
  const int C0 = split * 2048;                // this block's first col

  short8 a[4][8];
#pragma unroll
  for (int rf = 0; rf < 4; ++rf)
#pragma unroll
    for (int ks = 0; ks < 8; ++ks)
      a[rf][ks] = *(const short8*)(srcf + (((size_t)(R0 / 16 + rf) * 8 + ks) * 64 + l) * 8);

  float t3[4][4][3];
#pragma unroll
  for (int rf = 0; rf < 4; ++rf)
#pragma unroll
    for (int j = 0; j < 4; ++j) { t3[rf][j][0] = 1e30f; t3[rf][j][1] = 1e30f; t3[rf][j][2] = 1e30f; }

  const unsigned short* gb0 = tgtf + (size_t)(C0 / 16) * 4096;
#define STAGE(bsel, t)                                                        \
  {                                                                           \
    const unsigned short* gb = gb0 + (size_t)(t) * 16384;                     \
    _Pragma("unroll") for (int i = 0; i < 4; ++i) {                           \
      int chunk = w * 4 + i;                                                  \
      gload16(gb + chunk * 512 + l * 8, &buf[bsel][chunk * 512]);             \
    }                                                                         \
  }

  STAGE(0, 0);
  __syncthreads();

  for (int t = 0; t < 32; ++t) {
    int cur = t & 1;
    if (t < 31) STAGE(cur ^ 1, t + 1);
    int colbase = C0 + t * 64;
#pragma unroll
    for (int cf = 0; cf < 4; ++cf) {
      float t2c = t2[colbase + cf * 16 + (l & 15)];
      floatx4 acc[4];
#pragma unroll
      for (int rf = 0; rf < 4; ++rf) acc[rf] = (floatx4){0.f, 0.f, 0.f, 0.f};
#pragma unroll
      for (int ks = 0; ks < 8; ++ks) {
        short8 bfr = *(const short8*)(&buf[cur][(cf * 8 + ks) * 512 + l * 8]);
#pragma unroll
        for (int rf = 0; rf < 4; ++rf) acc[rf] = MFMA16(a[rf][ks], bfr, acc[rf]);
      }
#pragma unroll
      for (int rf = 0; rf < 4; ++rf)
#pragma unroll
        for (int j = 0; j < 4; ++j)
          ins3(t3[rf][j][0], t3[rf][j][1], t3[rf][j][2], fmaf(-2.f, acc[rf][j], t2c));
    }
    __syncthreads();
  }
#undef STAGE

#pragma unroll
  for (int rf = 0; rf < 4; ++rf)
#pragma unroll
    for (int j = 0; j < 4; ++j)
#pragma unroll
      for (int m = 1; m < 16; m <<= 1) {
        float o0 = __shfl_xor(t3[rf][j][0], m, 64);
        float o1 = __shfl_xor(t3[rf][j][1], m, 64);
        float o2 = __shfl_xor(t3[rf][j][2], m, 64);
        ins3(t3[rf][j][0], t3[rf][j][1], t3[rf][j][2], o0);
        ins3(t3[rf][j][0], t3[rf][j][1], t3[rf][j][2], o1);
        ins3(t3[rf][j][0], t3[rf][j][1], t3[rf][j][2], o2);
      }
  if ((l & 15) == 0) {
    int q = l >> 4;
#pragma unroll
    for (int rf = 0; rf < 4; ++rf)
#pragma unroll
      for (int j = 0; j < 4; ++j) {
        int row = R0 + rf * 16 + q * 4 + j;
        float* p = part + ((size_t)row * 8 + split) * 3;
        p[0] = t3[rf][j][0];
        p[1] = t3[rf][j][1];
        p[2] = t3[rf][j][2];
      }
  }
}

// ---------------------------------------------------------------------------
// merge: per row fold 8 splits x 3 candidates, add |s|^2, sqrt, entropy.
// ---------------------------------------------------------------------------
__global__ void merge_kernel(const float* __restrict__ part, const float* __restrict__ s2,
                             float* __restrict__ eout) {
  int r = blockIdx.x * 256 + threadIdx.x;  // 16384
  const float* p = part + (size_t)r * 24;
  float u0 = 1e30f, u1 = 1e30f, u2 = 1e30f;
#pragma unroll
  for (int i = 0; i < 24; ++i) ins3(u0, u1, u2, p[i]);
  float sv = s2[r];
  float d0 = sqrtf(fmaxf(sv + u0, 0.f));
  float d1 = sqrtf(fmaxf(sv + u1, 0.f));
  float d2 = sqrtf(fmaxf(sv + u2, 0.f));
  eout[r] = (d0 + d1 + d2) * 0.5f;
}

extern "C" void kernel_launch(void* const* d_in, const int* in_sizes, int n_in,
                              void* d_out, int out_size, void* d_ws, size_t ws_size,
                              hipStream_t stream) {
  const float* xsrc = (const float*)d_in[0];
  const float* xtgt = (const float*)d_in[1];
  const float* W1 = (const float*)d_in[2];
  const float* b1 = (const float*)d_in[3];
  const float* W2 = (const float*)d_in[4];
  const float* b2 = (const float*)d_in[5];
  const float* W3 = (const float*)d_in[6];
  const float* b3 = (const float*)d_in[7];
  const float* gm = (const float*)d_in[8];
  const float* bt = (const float*)d_in[9];
  float* out = (float*)d_out;
  unsigned short* ws16 = (unsigned short*)d_ws;

  prep_weights<<<80, 256, 0, stream>>>(W1, W2, W3, ws16);
  encode_kernel<<<512, 256, 0, stream>>>(xsrc, xtgt, b1, b2, b3, gm, bt, out, ws16);
  dist_kernel<<<256, 512, 0, stream>>>(ws16 + OFF_SRCF / 2, ws16 + OFF_TGTF / 2,
                                       (const float*)((char*)d_ws + OFF_T2),
                                       (float*)((char*)d_ws + OFF_P));
  merge_kernel<<<64, 256, 0, stream>>>((const float*)((char*)d_ws + OFF_P),
                                       (const float*)((char*)d_ws + OFF_S2),
                                       out + 4194304);
}